// Round 5
// baseline (853.522 us; speedup 1.0000x reference)
//
#include <hip/hip_runtime.h>
#include <hip/hip_bf16.h>
#include <hip/hip_cooperative_groups.h>

namespace cg = cooperative_groups;

// GCN on MI355X — R19: dispatch-count attack (13 -> 8).
// Established by R14-R18 elimination:
//   * k_agg is L2-miss-BYTE bound at ~2.9-3.2 TB/s; best form is the R14/R15
//     2-node wave gather (43.0us, FETCH 126.6MB, near the ~102MB 8-XCD
//     compulsory floor). Instruction count / MLP / VALU load all irrelevant.
//     fp8 rows are the only remaining traffic lever (accuracy-risky; parked).
//   * prep = total - 3*agg ~= 214us across 10 dispatches whose ideal traffic
//     is < 50us -> launch gaps + drain dominate. So: fuse.
// R19 pipeline (8 dispatches):
//   k_csr      - COOPERATIVE: bhist+wprep+zero | colscan | bscan | bucket |
//                sort(+csr_w fill) with grid.sync() between phases
//   k_gemm     - layer-1 GEMM (x fp32 -> hW bf16)
//   k_agg x3   - R15 readlane 2-node gather (proven best)
//   k_gemm x2  - MFMA 16x16x32 bf16, bias+relu fused
//   k_poolfinal- COOPERATIVE: run-length pool | grid.sync | classifier
// All ws-derived loop bounds are clamped (rocprof counter-replay safety).

#define BSHIFT 7
#define BNODES (1 << BSHIFT)
#define EPB    8192
#define MAXDEG 8192
#define MAXBUCKET 32768

typedef __attribute__((ext_vector_type(8))) short bf16x8;
typedef __attribute__((ext_vector_type(4))) float f32x4;

__device__ __forceinline__ void atomAddF(float* p, float v) {
#if defined(__gfx90a__) || defined(__gfx940__) || defined(__gfx941__) || defined(__gfx942__) || defined(__gfx950__)
    unsafeAtomicAdd(p, v);
#else
    atomicAdd(p, v);
#endif
}

__device__ __forceinline__ unsigned short f2bf(float x) {   // RNE fp32->bf16
    unsigned u = __float_as_uint(x);
    u += 0x7FFFu + ((u >> 16) & 1u);
    return (unsigned short)(u >> 16);
}
__device__ __forceinline__ float bf2f(unsigned short b) {
    return __uint_as_float((unsigned)b << 16);
}

// ---------------- COOPERATIVE CSR build -------------------------------------
// Phase A: per-block bucket histogram (+ weight prep + pool zero)
// Phase B: column scan (one wave per bucket)
// Phase C: bucket scan (block 0)
// Phase D: bucket placement
// Phase E1: per-bucket counting sort (counts/scan/rowptr/rowend/dinv)
// Phase E2: scatter csr_s + csr_w (= dinv[src], valid after the E1 sync)
// NOTE: no early returns — every thread reaches every grid.sync().
__global__ __launch_bounds__(256)
void k_csr(const int* __restrict__ src, const int* __restrict__ dst,
           int* __restrict__ cnt_all, int* __restrict__ bcnt,
           int* __restrict__ bbase, int* __restrict__ staging,
           int* __restrict__ csr_s, float* __restrict__ csr_w,
           int* __restrict__ rowptr, int* __restrict__ rowend,
           float* __restrict__ dinv,
           const float* __restrict__ W1, const float* __restrict__ W2,
           const float* __restrict__ W3, unsigned short* __restrict__ Wt,
           float* __restrict__ pool, int poolN,
           int nE, int n, int nBuckets, int binBlocks) {
    cg::grid_group grid = cg::this_grid();
    __shared__ int sA[1024];
    __shared__ int sB[1024];
    const int t   = threadIdx.x;
    const int bid = blockIdx.x;

    // ---- Phase A ----
    if (bid < binBlocks) {
        for (int b = t; b < nBuckets; b += 256) sA[b] = 0;
        __syncthreads();
        const int blk = bid * EPB;
#pragma unroll 4
        for (int i = 0; i < EPB / 256; i++) {
            int e = blk + i * 256 + t;
            if (e < nE) atomicAdd(&sA[dst[e] >> BSHIFT], 1);
        }
        __syncthreads();
        for (int b = t; b < nBuckets; b += 256)
            cnt_all[(size_t)bid * nBuckets + b] = sA[b];
    } else if (bid < binBlocks + 3) {
        int li = bid - binBlocks;
        const float* W = (li == 0) ? W1 : ((li == 1) ? W2 : W3);
        unsigned short* o = Wt + li * 4096;
        for (int idx = t; idx < 4096; idx += 256) {
            int h = idx >> 6, k = idx & 63;
            o[idx] = f2bf(W[k * 64 + h]);
        }
    } else if (bid == binBlocks + 3) {
        for (int i = t; i < poolN; i += 256) pool[i] = 0.f;
    }
    grid.sync();

    // ---- Phase B: column scan ----
    {
        const int lane = t & 63;
        const int b = bid * 4 + (t >> 6);
        if (b < nBuckets) {
            int running = 0;
            for (int c = 0; c < binBlocks; c += 64) {
                int blk2 = c + lane;
                int v = (blk2 < binBlocks) ? cnt_all[(size_t)blk2 * nBuckets + b] : 0;
                int incl = v;
#pragma unroll
                for (int off = 1; off < 64; off <<= 1) {
                    int tv = __shfl_up(incl, off);
                    if (lane >= off) incl += tv;
                }
                if (blk2 < binBlocks)
                    cnt_all[(size_t)blk2 * nBuckets + b] = running + (incl - v);
                running += __shfl(incl, 63);
            }
            if (lane == 0) bcnt[b] = running;
        }
    }
    grid.sync();

    // ---- Phase C: bucket scan (block 0, nBuckets <= 1024) ----
    if (bid == 0) {
        const int base = t * 4;
        int v0 = (base + 0 < nBuckets) ? bcnt[base + 0] : 0;
        int v1 = (base + 1 < nBuckets) ? bcnt[base + 1] : 0;
        int v2 = (base + 2 < nBuckets) ? bcnt[base + 2] : 0;
        int v3 = (base + 3 < nBuckets) ? bcnt[base + 3] : 0;
        int tsum = v0 + v1 + v2 + v3;
        sA[t] = tsum;
        __syncthreads();
        for (int off = 1; off < 256; off <<= 1) {
            int val = 0;
            if (t >= off) val = sA[t - off];
            __syncthreads();
            if (t >= off) sA[t] += val;
            __syncthreads();
        }
        int excl = sA[t] - tsum;
        if (base + 0 < nBuckets) bbase[base + 0] = excl;
        if (base + 1 < nBuckets) bbase[base + 1] = excl + v0;
        if (base + 2 < nBuckets) bbase[base + 2] = excl + v0 + v1;
        if (base + 3 < nBuckets) bbase[base + 3] = excl + v0 + v1 + v2;
        if (t == 0) bbase[nBuckets] = nE;
    }
    grid.sync();

    // ---- Phase D: bucket placement ----
    if (bid < binBlocks) {
        for (int b = t; b < nBuckets; b += 256) {
            sB[b] = bbase[b] + cnt_all[(size_t)bid * nBuckets + b];
            sA[b] = 0;
        }
        __syncthreads();
        const int blk = bid * EPB;
#pragma unroll 4
        for (int i = 0; i < EPB / 256; i++) {
            int e = blk + i * 256 + t;
            if (e < nE) {
                int s0 = src[e], d0 = dst[e];
                int b = d0 >> BSHIFT;
                int off = atomicAdd(&sA[b], 1);
                int pos = sB[b] + off;
                if ((unsigned)pos < (unsigned)nE)
                    staging[pos] = (s0 << BSHIFT) | (d0 & (BNODES - 1));
            }
        }
    }
    grid.sync();

    // ---- Phase E1: counting sort (block bid = bucket bid) ----
    int seg0 = 0, seg1 = 0;
    {
        int* c   = sA;          // [0..127]
        int* sc  = sA + 128;    // [128..255]
        int* cur = sA + 256;    // [256..383]
        const int node0 = bid << BSHIFT;
        seg0 = bbase[bid];
        seg1 = bbase[bid + 1];
        seg0 = max(0, min(seg0, nE));
        seg1 = max(seg0, min(seg1, nE));
        seg1 = min(seg1, seg0 + MAXBUCKET);

        if (t < BNODES) c[t] = 0;
        __syncthreads();
        for (int e = seg0 + t; e < seg1; e += 256)
            atomicAdd(&c[staging[e] & (BNODES - 1)], 1);
        __syncthreads();
        if (t < BNODES) sc[t] = c[t];
        __syncthreads();
        for (int off = 1; off < BNODES; off <<= 1) {
            int v = 0;
            if (t >= off && t < BNODES) v = sc[t - off];
            __syncthreads();
            if (t >= off && t < BNODES) sc[t] += v;
            __syncthreads();
        }
        if (t < BNODES) {
            int excl = sc[t] - c[t];
            cur[t] = excl;
            int node = node0 + t;
            if (node < n) {
                rowptr[node] = seg0 + excl;
                rowend[node] = seg0 + excl + c[t];
                dinv[node]   = rsqrtf((float)c[t] + 1.0f);
            }
        }
    }
    grid.sync();   // all dinv visible device-wide

    // ---- Phase E2: scatter csr_s + csr_w ----
    {
        int* cur = sA + 256;    // persists across grid.sync
        const int nm1 = n - 1;
        for (int e = seg0 + t; e < seg1; e += 256) {
            int p = staging[e];
            int l = p & (BNODES - 1);
            int pos = seg0 + atomicAdd(&cur[l], 1);
            if ((unsigned)pos < (unsigned)nE) {
                int sidx = (int)(((unsigned)p) >> BSHIFT);
                csr_s[pos] = sidx;
                sidx = max(0, min(sidx, nm1));
                csr_w[pos] = dinv[sidx];
            }
        }
    }
}

// ---------------- MFMA GEMM -------------------------------------------------
template<bool RELU, typename AT>
__device__ __forceinline__
void gemm_body(int bid, const AT* __restrict__ in,
               const unsigned short* __restrict__ Wt,
               const float* __restrict__ bias,
               unsigned short* __restrict__ out, int n) {
    const int lane = threadIdx.x & 63;
    const int wid  = threadIdx.x >> 6;
    const int col  = lane & 15;
    const int quad = lane >> 4;
    const int node0w = bid * 64 + wid * 16;
    const int nodeA  = node0w + col;
    const bool validA = nodeA < n;

    f32x4 zero4 = {0.f, 0.f, 0.f, 0.f};
    f32x4 acc0 = zero4, acc1 = zero4, acc2 = zero4, acc3 = zero4;

#pragma unroll
    for (int ks = 0; ks < 64; ks += 32) {
        const int kb = ks + quad * 8;
        float a[8];
        if constexpr (sizeof(AT) == 4) {
            float4 a0 = make_float4(0.f, 0.f, 0.f, 0.f);
            float4 a1 = make_float4(0.f, 0.f, 0.f, 0.f);
            if (validA) {
                a0 = *(const float4*)((const float*)in + (size_t)nodeA * 64 + kb);
                a1 = *(const float4*)((const float*)in + (size_t)nodeA * 64 + kb + 4);
            }
            a[0] = a0.x; a[1] = a0.y; a[2] = a0.z; a[3] = a0.w;
            a[4] = a1.x; a[5] = a1.y; a[6] = a1.z; a[7] = a1.w;
        } else {
            ushort4 h0 = make_ushort4(0, 0, 0, 0), h1 = make_ushort4(0, 0, 0, 0);
            if (validA) {
                h0 = *(const ushort4*)((const unsigned short*)in + (size_t)nodeA * 64 + kb);
                h1 = *(const ushort4*)((const unsigned short*)in + (size_t)nodeA * 64 + kb + 4);
            }
            a[0] = bf2f(h0.x); a[1] = bf2f(h0.y); a[2] = bf2f(h0.z); a[3] = bf2f(h0.w);
            a[4] = bf2f(h1.x); a[5] = bf2f(h1.y); a[6] = bf2f(h1.z); a[7] = bf2f(h1.w);
        }
        if (RELU) {
#pragma unroll
            for (int i = 0; i < 8; i++) a[i] = fmaxf(a[i] + bias[kb + i], 0.f);
        }
        bf16x8 af;
#pragma unroll
        for (int i = 0; i < 8; i++) af[i] = (short)f2bf(a[i]);

        const bf16x8 b0f = *(const bf16x8*)(Wt + ((0 * 16 + col) * 64 + kb));
        const bf16x8 b1f = *(const bf16x8*)(Wt + ((1 * 16 + col) * 64 + kb));
        const bf16x8 b2f = *(const bf16x8*)(Wt + ((2 * 16 + col) * 64 + kb));
        const bf16x8 b3f = *(const bf16x8*)(Wt + ((3 * 16 + col) * 64 + kb));
        acc0 = __builtin_amdgcn_mfma_f32_16x16x32_bf16(af, b0f, acc0, 0, 0, 0);
        acc1 = __builtin_amdgcn_mfma_f32_16x16x32_bf16(af, b1f, acc1, 0, 0, 0);
        acc2 = __builtin_amdgcn_mfma_f32_16x16x32_bf16(af, b2f, acc2, 0, 0, 0);
        acc3 = __builtin_amdgcn_mfma_f32_16x16x32_bf16(af, b3f, acc3, 0, 0, 0);
    }

#pragma unroll
    for (int r = 0; r < 4; r++) {
        int nn = node0w + quad * 4 + r;
        if (nn < n) {
            size_t base = (size_t)nn * 64 + col;
            out[base +  0] = f2bf(acc0[r]);
            out[base + 16] = f2bf(acc1[r]);
            out[base + 32] = f2bf(acc2[r]);
            out[base + 48] = f2bf(acc3[r]);
        }
    }
}

template<bool RELU, typename AT>
__global__ __launch_bounds__(256)
void k_gemm(const AT* __restrict__ in, const unsigned short* __restrict__ Wt,
            const float* __restrict__ bias, unsigned short* __restrict__ out, int n) {
    gemm_body<RELU, AT>(blockIdx.x, in, Wt, bias, out, n);
}

// ---------------- aggregation: two nodes per wave, readlane broadcast ---------
// R15 form — best measured (43.0us, FETCH 126.6MB ~ near compulsory floor).
template<int LAYER>
__global__ __launch_bounds__(256)
void k_agg(const unsigned short* __restrict__ hW, const int* __restrict__ rowptr,
           const int* __restrict__ rowend, const int* __restrict__ csr_s,
           const float* __restrict__ csr_w, const float* __restrict__ dinv,
           unsigned short* __restrict__ aggb, int n, int nE) {
    const int lane = threadIdx.x & 63;
    const int wid  = threadIdx.x >> 6;
    const int nA = blockIdx.x * 8 + wid * 2;
    const int nB = nA + 1;
    if (nA >= n) return;
    const bool vB = (nB < n);

    int rowA = rowptr[nA], endA = rowend[nA];
    rowA = max(0, min(rowA, nE)); endA = max(rowA, min(endA, nE));
    endA = min(endA, rowA + MAXDEG);
    int rowB = 0, endB = 0;
    if (vB) {
        rowB = rowptr[nB]; endB = rowend[nB];
        rowB = max(0, min(rowB, nE)); endB = max(rowB, min(endB, nE));
        endB = min(endB, rowB + MAXDEG);
    }
    const float diA = dinv[nA];
    const float diB = vB ? dinv[nB] : 0.f;

    float a0 = diA * diA * bf2f(hW[(size_t)nA * 64 + lane]);
    float a1 = 0.f, a2 = 0.f, a3 = 0.f;
    float b0 = vB ? diB * diB * bf2f(hW[(size_t)nB * 64 + lane]) : 0.f;
    float b1 = 0.f, b2 = 0.f, b3 = 0.f;

    const int nm1 = n - 1;
    int baseA = rowA, baseB = rowB;
    while (baseA < endA || baseB < endB) {
        int mA = max(0, min(32, endA - baseA));
        int mB = max(0, min(32, endB - baseB));
        int   s_l = 0;
        float w_l = 0.f;
        if (lane < 32) {
            if (lane < mA) {
                int e = baseA + lane;
                s_l = csr_s[e];
                w_l = csr_w[e] * diA;
            }
        } else {
            int l2 = lane - 32;
            if (l2 < mB) {
                int e = baseB + l2;
                s_l = csr_s[e];
                w_l = csr_w[e] * diB;
            }
        }
        const unsigned w_u = __float_as_uint(w_l);
        const int m = max(mA, mB);
        int j = 0;
        for (; j + 4 <= m; j += 4) {
            int sA0 = min(__builtin_amdgcn_readlane(s_l, j    ), nm1);
            int sA1 = min(__builtin_amdgcn_readlane(s_l, j + 1), nm1);
            int sA2 = min(__builtin_amdgcn_readlane(s_l, j + 2), nm1);
            int sA3 = min(__builtin_amdgcn_readlane(s_l, j + 3), nm1);
            int sB0 = min(__builtin_amdgcn_readlane(s_l, j + 32), nm1);
            int sB1 = min(__builtin_amdgcn_readlane(s_l, j + 33), nm1);
            int sB2 = min(__builtin_amdgcn_readlane(s_l, j + 34), nm1);
            int sB3 = min(__builtin_amdgcn_readlane(s_l, j + 35), nm1);
            float wA0 = __uint_as_float(__builtin_amdgcn_readlane(w_u, j));
            float wA1 = __uint_as_float(__builtin_amdgcn_readlane(w_u, j + 1));
            float wA2 = __uint_as_float(__builtin_amdgcn_readlane(w_u, j + 2));
            float wA3 = __uint_as_float(__builtin_amdgcn_readlane(w_u, j + 3));
            float wB0 = __uint_as_float(__builtin_amdgcn_readlane(w_u, j + 32));
            float wB1 = __uint_as_float(__builtin_amdgcn_readlane(w_u, j + 33));
            float wB2 = __uint_as_float(__builtin_amdgcn_readlane(w_u, j + 34));
            float wB3 = __uint_as_float(__builtin_amdgcn_readlane(w_u, j + 35));
            float hA0 = bf2f(hW[(size_t)sA0 * 64 + lane]);
            float hA1 = bf2f(hW[(size_t)sA1 * 64 + lane]);
            float hA2 = bf2f(hW[(size_t)sA2 * 64 + lane]);
            float hA3 = bf2f(hW[(size_t)sA3 * 64 + lane]);
            float hB0 = bf2f(hW[(size_t)sB0 * 64 + lane]);
            float hB1 = bf2f(hW[(size_t)sB1 * 64 + lane]);
            float hB2 = bf2f(hW[(size_t)sB2 * 64 + lane]);
            float hB3 = bf2f(hW[(size_t)sB3 * 64 + lane]);
            a0 += wA0 * hA0; a1 += wA1 * hA1;
            a2 += wA2 * hA2; a3 += wA3 * hA3;
            b0 += wB0 * hB0; b1 += wB1 * hB1;
            b2 += wB2 * hB2; b3 += wB3 * hB3;
        }
        for (; j < m; j++) {
            int   sA = min(__builtin_amdgcn_readlane(s_l, j), nm1);
            int   sB = min(__builtin_amdgcn_readlane(s_l, j + 32), nm1);
            float wA = __uint_as_float(__builtin_amdgcn_readlane(w_u, j));
            float wB = __uint_as_float(__builtin_amdgcn_readlane(w_u, j + 32));
            a0 += wA * bf2f(hW[(size_t)sA * 64 + lane]);
            b0 += wB * bf2f(hW[(size_t)sB * 64 + lane]);
        }
        baseA += mA;
        baseB += mB;
    }
    aggb[(size_t)nA * 64 + lane] = f2bf((a0 + a1) + (a2 + a3));
    if (vB) aggb[(size_t)nB * 64 + lane] = f2bf((b0 + b1) + (b2 + b3));
}

// ---------------- COOPERATIVE pool + classifier -------------------------------
__global__ __launch_bounds__(256)
void k_poolfinal(const unsigned short* __restrict__ aggb,
                 const int* __restrict__ batch,
                 float* __restrict__ pool, float* __restrict__ cnt,
                 const float* __restrict__ b3, const float* __restrict__ Wl,
                 const float* __restrict__ bl, float* __restrict__ out,
                 int n, int G) {
    cg::grid_group grid = cg::this_grid();
    const int lane = threadIdx.x & 63;
    const int wid  = threadIdx.x >> 6;
    const int base = (blockIdx.x * 4 + wid) * 64;

    if (base < n) {                     // run-length pre-reduce (no return!)
        int g_cur = -1, run = 0;
        float acc = 0.f;
        for (int j = 0; j < 64; j++) {
            int node = base + j;
            if (node >= n) break;
            int g = batch[node];
            if (g != g_cur) {
                if (g_cur >= 0) {
                    atomAddF(&pool[g_cur * 64 + lane], acc);
                    if (lane == 0) atomAddF(&cnt[g_cur], (float)run);
                }
                g_cur = g; acc = 0.f; run = 0;
            }
            acc += bf2f(aggb[(size_t)node * 64 + lane]);
            run++;
        }
        if (g_cur >= 0) {
            atomAddF(&pool[g_cur * 64 + lane], acc);
            if (lane == 0) atomAddF(&cnt[g_cur], (float)run);
        }
    }
    grid.sync();

    // classifier: block g computes graph g
    const int g = blockIdx.x;
    __shared__ float s[64];
    if (g < G) {
        const int t = threadIdx.x;
        if (t < 64) {
            float c = fmaxf(cnt[g], 1.0f);
            s[t] = pool[g * 64 + t] / c + b3[t];
        }
        __syncthreads();
        if (t < 10) {
            float acc = bl[t];
#pragma unroll
            for (int k = 0; k < 64; k++) acc += s[k] * Wl[k * 10 + t];
            out[g * 10 + t] = acc;
        }
    }
}

extern "C" void kernel_launch(void* const* d_in, const int* in_sizes, int n_in,
                              void* d_out, int out_size, void* d_ws, size_t ws_size,
                              hipStream_t stream) {
    const float* x   = (const float*)d_in[0];
    const int*   ei  = (const int*)d_in[1];
    const int*   bat = (const int*)d_in[2];
    const float* W1  = (const float*)d_in[3];
    const float* b1  = (const float*)d_in[4];
    const float* W2  = (const float*)d_in[5];
    const float* b2  = (const float*)d_in[6];
    const float* W3  = (const float*)d_in[7];
    const float* b3  = (const float*)d_in[8];
    const float* Wl  = (const float*)d_in[9];
    const float* bl  = (const float*)d_in[10];
    float* out = (float*)d_out;

    int N_ = in_sizes[0] / 64;
    int E_ = in_sizes[1] / 2;
    int G_ = out_size / 10;
    int NB_ = (N_ + BNODES - 1) >> BSHIFT;
    int bin_blocks = (E_ + EPB - 1) / EPB;

    // workspace layout
    char* p = (char*)d_ws;
    int*   staging = (int*)p;   p += (size_t)E_ * 4;
    int*   csr_s  = (int*)p;    p += (size_t)E_ * 4;
    float* csr_w  = (float*)p;  p += (size_t)E_ * 4;
    unsigned short* aggb = (unsigned short*)p; p += (size_t)N_ * 64 * 2;
    unsigned short* hW   = (unsigned short*)p; p += (size_t)N_ * 64 * 2;
    float* dinv   = (float*)p;  p += (size_t)N_ * 4;
    int*   rowptr = (int*)p;    p += (size_t)N_ * 4;
    int*   rowend = (int*)p;    p += (size_t)N_ * 4;
    float* pool   = (float*)p;  p += (size_t)G_ * 64 * 4;
    float* cnt    = (float*)p;  p += (size_t)G_ * 4;
    unsigned short* Wt = (unsigned short*)p; p += 3 * 4096 * 2;
    int*   bcnt   = (int*)p;    p += (size_t)(NB_ + 1) * 4;
    int*   bbase  = (int*)p;    p += (size_t)(NB_ + 1) * 4;
    int*   cnt_all = (int*)p;   p += (size_t)bin_blocks * NB_ * 4;

    const int* srcp = ei;
    const int* dstp = ei + E_;
    int poolN = G_ * 64 + G_;

    // ---- 1) cooperative CSR build (5 dispatches -> 1) ----
    {
        int NBLK = bin_blocks + 4;
        if ((NB_ + 3) / 4 > NBLK) NBLK = (NB_ + 3) / 4;
        if (NB_ > NBLK) NBLK = NB_;
        void* args[] = { (void*)&srcp, (void*)&dstp, (void*)&cnt_all, (void*)&bcnt,
                         (void*)&bbase, (void*)&staging, (void*)&csr_s, (void*)&csr_w,
                         (void*)&rowptr, (void*)&rowend, (void*)&dinv,
                         (void*)&W1, (void*)&W2, (void*)&W3, (void*)&Wt,
                         (void*)&pool, (void*)&poolN,
                         (void*)&E_, (void*)&N_, (void*)&NB_, (void*)&bin_blocks };
        hipLaunchCooperativeKernel((void*)k_csr, dim3(NBLK), dim3(256),
                                   args, 0, stream);
    }

    const int gemm_blocks = (N_ + 63) / 64;
    const int agg_blocks  = (N_ + 7) / 8;

    // ---- 2) layer-1 GEMM ----
    k_gemm<false, float><<<gemm_blocks, 256, 0, stream>>>(x, Wt, nullptr, hW, N_);
    // ---- 3) agg 1 ----
    k_agg<1><<<agg_blocks, 256, 0, stream>>>(hW, rowptr, rowend, csr_s, csr_w,
                                             dinv, aggb, N_, E_);
    // ---- 4) layer-2 GEMM ----
    k_gemm<true, unsigned short><<<gemm_blocks, 256, 0, stream>>>(aggb, Wt + 4096,
                                                                  b1, hW, N_);
    // ---- 5) agg 2 ----
    k_agg<2><<<agg_blocks, 256, 0, stream>>>(hW, rowptr, rowend, csr_s, csr_w,
                                             dinv, aggb, N_, E_);
    // ---- 6) layer-3 GEMM ----
    k_gemm<true, unsigned short><<<gemm_blocks, 256, 0, stream>>>(aggb, Wt + 8192,
                                                                  b2, hW, N_);
    // ---- 7) agg 3 ----
    k_agg<3><<<agg_blocks, 256, 0, stream>>>(hW, rowptr, rowend, csr_s, csr_w,
                                             dinv, aggb, N_, E_);

    // ---- 8) cooperative pool + classifier (2 dispatches -> 1) ----
    {
        int PF = (N_ + 255) / 256;
        if (G_ > PF) PF = G_;
        void* args[] = { (void*)&aggb, (void*)&bat, (void*)&pool, (void*)&cnt,
                         (void*)&b3, (void*)&Wl, (void*)&bl, (void*)&out,
                         (void*)&N_, (void*)&G_ };
        hipLaunchCooperativeKernel((void*)k_poolfinal, dim3(PF), dim3(256),
                                   args, 0, stream);
    }
}

// Round 6
// 335.113 us; speedup vs baseline: 2.5470x; 2.5470x over previous
//
#include <hip/hip_runtime.h>
#include <hip/hip_bf16.h>

// GCN on MI355X — R20: int8 row-quantized gather rows (64B/row, was 128B).
// ACCOUNTING (solved in R19): total = ~174us harness poison-fills (fixed)
//   + 3 x k_agg + ~36us prep. Prep is NOT the pot; agg traffic is.
// Agg wall (R14-R18): constant ~2.9-3.2 TB/s L2-miss traffic; lines and
// bytes co-varied in all probes (128B bf16 row = 2 lines); R17 ruled out
// instruction rate. int8 rows halve BOTH bytes and lines.
// GEMMs emit hW (bf16, for self term + verification path) AND hQ (int8,
// row-scaled; scale[] is N floats, L2-resident, folded into per-edge w).
// Cooperative fusion is DEAD (R19: grid.sync ~100us at 780 blocks).
// Pipeline (13 dispatches), all R15-proven forms otherwise:
//   k_bhist   - per-block bucket histogram + wprep + pool zeroing
//   k_colscan / k_bscan / k_bucket / k_sort - CSR build
//   k_wfgemm1 - FUSED wfill + layer-1 GEMM (+ int8 quant epilogue)
//   k_agg x3  - R15 readlane 2-node form, int8 gathers
//   k_gemm x2 - MFMA 16x16x32 bf16, bias+relu fused (+ int8 quant epilogue)
//   k_pool    - run-length pre-reduce;  k_final
// All ws-derived loop bounds are clamped (rocprof counter-replay safety).

#define BSHIFT 7
#define BNODES (1 << BSHIFT)
#define EPB    8192
#define MAXDEG 8192
#define MAXBUCKET 32768

typedef __attribute__((ext_vector_type(8))) short bf16x8;
typedef __attribute__((ext_vector_type(4))) float f32x4;

__device__ __forceinline__ void atomAddF(float* p, float v) {
#if defined(__gfx90a__) || defined(__gfx940__) || defined(__gfx941__) || defined(__gfx942__) || defined(__gfx950__)
    unsafeAtomicAdd(p, v);
#else
    atomicAdd(p, v);
#endif
}

__device__ __forceinline__ unsigned short f2bf(float x) {   // RNE fp32->bf16
    unsigned u = __float_as_uint(x);
    u += 0x7FFFu + ((u >> 16) & 1u);
    return (unsigned short)(u >> 16);
}
__device__ __forceinline__ float bf2f(unsigned short b) {
    return __uint_as_float((unsigned)b << 16);
}

// ---------------- histogram + weight prep + pool zeroing ----------------
__global__ __launch_bounds__(256)
void k_bhist(const int* __restrict__ dst, int* __restrict__ cnt_all,
             int nE, int nBuckets, int binBlocks,
             const float* __restrict__ W1, const float* __restrict__ W2,
             const float* __restrict__ W3, unsigned short* __restrict__ Wt,
             float* __restrict__ pool, int poolN) {
    if (blockIdx.x >= binBlocks) {
        int li = blockIdx.x - binBlocks;          // 0..2 wprep, 3 = pool zero
        if (li < 3) {
            const float* W = (li == 0) ? W1 : ((li == 1) ? W2 : W3);
            unsigned short* o = Wt + li * 4096;
            for (int idx = threadIdx.x; idx < 4096; idx += 256) {
                int h = idx >> 6, k = idx & 63;
                o[idx] = f2bf(W[k * 64 + h]);
            }
        } else {
            for (int i = threadIdx.x; i < poolN; i += 256) pool[i] = 0.f;
        }
        return;
    }
    __shared__ int cnt[1024];
    const int t = threadIdx.x;
    const int blk = blockIdx.x * EPB;
    for (int b = t; b < nBuckets; b += 256) cnt[b] = 0;
    __syncthreads();
#pragma unroll 4
    for (int i = 0; i < EPB / 256; i++) {
        int e = blk + i * 256 + t;
        if (e < nE) atomicAdd(&cnt[dst[e] >> BSHIFT], 1);
    }
    __syncthreads();
    for (int b = t; b < nBuckets; b += 256)
        cnt_all[(size_t)blockIdx.x * nBuckets + b] = cnt[b];
}

// ---------------- column scan: one wave per bucket ----------------
__global__ __launch_bounds__(256)
void k_colscan(int* __restrict__ cnt_all, int* __restrict__ bcnt,
               int nBlocks, int nBuckets) {
    const int lane = threadIdx.x & 63;
    const int b = blockIdx.x * 4 + (threadIdx.x >> 6);
    if (b >= nBuckets) return;
    int running = 0;
    for (int c = 0; c < nBlocks; c += 64) {
        int blk = c + lane;
        int v = (blk < nBlocks) ? cnt_all[(size_t)blk * nBuckets + b] : 0;
        int incl = v;
#pragma unroll
        for (int off = 1; off < 64; off <<= 1) {
            int tv = __shfl_up(incl, off);
            if (lane >= off) incl += tv;
        }
        if (blk < nBlocks) cnt_all[(size_t)blk * nBuckets + b] = running + (incl - v);
        running += __shfl(incl, 63);
    }
    if (lane == 0) bcnt[b] = running;
}

// ---------------- bucket scan (nb <= 1024) -> bbase ----------------
__global__ void k_bscan(const int* __restrict__ bcnt, int* __restrict__ bbase,
                        int nb, int nE) {
    __shared__ int s[256];
    const int t = threadIdx.x;
    const int base = t * 4;
    int v0 = (base + 0 < nb) ? bcnt[base + 0] : 0;
    int v1 = (base + 1 < nb) ? bcnt[base + 1] : 0;
    int v2 = (base + 2 < nb) ? bcnt[base + 2] : 0;
    int v3 = (base + 3 < nb) ? bcnt[base + 3] : 0;
    int tsum = v0 + v1 + v2 + v3;
    s[t] = tsum;
    __syncthreads();
    for (int off = 1; off < 256; off <<= 1) {
        int val = 0;
        if (t >= off) val = s[t - off];
        __syncthreads();
        if (t >= off) s[t] += val;
        __syncthreads();
    }
    int excl = s[t] - tsum;
    if (base + 0 < nb) bbase[base + 0] = excl;
    if (base + 1 < nb) bbase[base + 1] = excl + v0;
    if (base + 2 < nb) bbase[base + 2] = excl + v0 + v1;
    if (base + 3 < nb) bbase[base + 3] = excl + v0 + v1 + v2;
    if (t == 0) bbase[nb] = nE;
}

// ---------------- bucket placement ----------------
__global__ __launch_bounds__(256)
void k_bucket(const int* __restrict__ src, const int* __restrict__ dst,
              const int* __restrict__ bbase, const int* __restrict__ cnt_all,
              int* __restrict__ staging, int nE, int nBuckets) {
    __shared__ int cnt[1024];
    __shared__ int lbase[1024];
    const int t = threadIdx.x;
    const int blk = blockIdx.x * EPB;

    for (int b = t; b < nBuckets; b += 256) {
        lbase[b] = bbase[b] + cnt_all[(size_t)blockIdx.x * nBuckets + b];
        cnt[b] = 0;
    }
    __syncthreads();
#pragma unroll 4
    for (int i = 0; i < EPB / 256; i++) {
        int e = blk + i * 256 + t;
        if (e < nE) {
            int s0 = src[e], d0 = dst[e];
            int b = d0 >> BSHIFT;
            int off = atomicAdd(&cnt[b], 1);
            int pos = lbase[b] + off;
            if ((unsigned)pos < (unsigned)nE)
                staging[pos] = (s0 << BSHIFT) | (d0 & (BNODES - 1));
        }
    }
}

// ---------------- per-bucket counting sort -> CSR + rowptr/rowend/dinv ----------
__global__ __launch_bounds__(256)
void k_sort(const int* __restrict__ staging, const int* __restrict__ bbase,
            int* __restrict__ csr_s, int* __restrict__ rowptr,
            int* __restrict__ rowend, float* __restrict__ dinv,
            int n, int nE) {
    __shared__ int c[BNODES];
    __shared__ int sc[BNODES];
    __shared__ int cur[BNODES];
    const int t = threadIdx.x;
    const int b = blockIdx.x;
    const int node0 = b << BSHIFT;

    int seg0 = bbase[b];
    int seg1 = bbase[b + 1];
    seg0 = max(0, min(seg0, nE));
    seg1 = max(seg0, min(seg1, nE));
    seg1 = min(seg1, seg0 + MAXBUCKET);

    if (t < BNODES) c[t] = 0;
    __syncthreads();
    for (int e = seg0 + t; e < seg1; e += 256)
        atomicAdd(&c[staging[e] & (BNODES - 1)], 1);
    __syncthreads();
    if (t < BNODES) sc[t] = c[t];
    __syncthreads();
    for (int off = 1; off < BNODES; off <<= 1) {
        int v = 0;
        if (t >= off && t < BNODES) v = sc[t - off];
        __syncthreads();
        if (t >= off && t < BNODES) sc[t] += v;
        __syncthreads();
    }
    if (t < BNODES) {
        int excl = sc[t] - c[t];
        cur[t] = excl;
        int node = node0 + t;
        if (node < n) {
            rowptr[node] = seg0 + excl;
            rowend[node] = seg0 + excl + c[t];
            dinv[node]   = rsqrtf((float)c[t] + 1.0f);
        }
    }
    __syncthreads();
    for (int e = seg0 + t; e < seg1; e += 256) {
        int p = staging[e];
        int l = p & (BNODES - 1);
        int pos = seg0 + atomicAdd(&cur[l], 1);
        if ((unsigned)pos < (unsigned)nE)
            csr_s[pos] = ((unsigned)p) >> BSHIFT;
    }
}

// ---------------- MFMA GEMM body + int8 row-quant epilogue --------------------
template<bool RELU, typename AT>
__device__ __forceinline__
void gemm_body(int bid, const AT* __restrict__ in,
               const unsigned short* __restrict__ Wt,
               const float* __restrict__ bias,
               unsigned short* __restrict__ out,
               signed char* __restrict__ hQ,
               float* __restrict__ hscale, int n) {
    const int lane = threadIdx.x & 63;
    const int wid  = threadIdx.x >> 6;
    const int col  = lane & 15;
    const int quad = lane >> 4;
    const int node0w = bid * 64 + wid * 16;
    const int nodeA  = node0w + col;
    const bool validA = nodeA < n;

    f32x4 zero4 = {0.f, 0.f, 0.f, 0.f};
    f32x4 acc0 = zero4, acc1 = zero4, acc2 = zero4, acc3 = zero4;

#pragma unroll
    for (int ks = 0; ks < 64; ks += 32) {
        const int kb = ks + quad * 8;
        float a[8];
        if constexpr (sizeof(AT) == 4) {
            float4 a0 = make_float4(0.f, 0.f, 0.f, 0.f);
            float4 a1 = make_float4(0.f, 0.f, 0.f, 0.f);
            if (validA) {
                a0 = *(const float4*)((const float*)in + (size_t)nodeA * 64 + kb);
                a1 = *(const float4*)((const float*)in + (size_t)nodeA * 64 + kb + 4);
            }
            a[0] = a0.x; a[1] = a0.y; a[2] = a0.z; a[3] = a0.w;
            a[4] = a1.x; a[5] = a1.y; a[6] = a1.z; a[7] = a1.w;
        } else {
            ushort4 h0 = make_ushort4(0, 0, 0, 0), h1 = make_ushort4(0, 0, 0, 0);
            if (validA) {
                h0 = *(const ushort4*)((const unsigned short*)in + (size_t)nodeA * 64 + kb);
                h1 = *(const ushort4*)((const unsigned short*)in + (size_t)nodeA * 64 + kb + 4);
            }
            a[0] = bf2f(h0.x); a[1] = bf2f(h0.y); a[2] = bf2f(h0.z); a[3] = bf2f(h0.w);
            a[4] = bf2f(h1.x); a[5] = bf2f(h1.y); a[6] = bf2f(h1.z); a[7] = bf2f(h1.w);
        }
        if (RELU) {
#pragma unroll
            for (int i = 0; i < 8; i++) a[i] = fmaxf(a[i] + bias[kb + i], 0.f);
        }
        bf16x8 af;
#pragma unroll
        for (int i = 0; i < 8; i++) af[i] = (short)f2bf(a[i]);

        const bf16x8 b0f = *(const bf16x8*)(Wt + ((0 * 16 + col) * 64 + kb));
        const bf16x8 b1f = *(const bf16x8*)(Wt + ((1 * 16 + col) * 64 + kb));
        const bf16x8 b2f = *(const bf16x8*)(Wt + ((2 * 16 + col) * 64 + kb));
        const bf16x8 b3f = *(const bf16x8*)(Wt + ((3 * 16 + col) * 64 + kb));
        acc0 = __builtin_amdgcn_mfma_f32_16x16x32_bf16(af, b0f, acc0, 0, 0, 0);
        acc1 = __builtin_amdgcn_mfma_f32_16x16x32_bf16(af, b1f, acc1, 0, 0, 0);
        acc2 = __builtin_amdgcn_mfma_f32_16x16x32_bf16(af, b2f, acc2, 0, 0, 0);
        acc3 = __builtin_amdgcn_mfma_f32_16x16x32_bf16(af, b3f, acc3, 0, 0, 0);
    }

#pragma unroll
    for (int r = 0; r < 4; r++) {
        int nn = node0w + quad * 4 + r;
        // row max across the quad's 16 lanes (shfl_xor 1/2/4/8 stays in-quad)
        float m = fmaxf(fmaxf(fabsf(acc0[r]), fabsf(acc1[r])),
                        fmaxf(fabsf(acc2[r]), fabsf(acc3[r])));
#pragma unroll
        for (int off = 1; off < 16; off <<= 1)
            m = fmaxf(m, __shfl_xor(m, off));
        const float inv = (m > 0.f) ? (127.0f / m) : 0.f;
        if (nn < n) {
            size_t base = (size_t)nn * 64 + col;
            out[base +  0] = f2bf(acc0[r]);
            out[base + 16] = f2bf(acc1[r]);
            out[base + 32] = f2bf(acc2[r]);
            out[base + 48] = f2bf(acc3[r]);
            hQ[base +  0] = (signed char)__float2int_rn(acc0[r] * inv);
            hQ[base + 16] = (signed char)__float2int_rn(acc1[r] * inv);
            hQ[base + 32] = (signed char)__float2int_rn(acc2[r] * inv);
            hQ[base + 48] = (signed char)__float2int_rn(acc3[r] * inv);
            if (col == 0) hscale[nn] = m * (1.0f / 127.0f);
        }
    }
}

template<bool RELU, typename AT>
__global__ __launch_bounds__(256)
void k_gemm(const AT* __restrict__ in, const unsigned short* __restrict__ Wt,
            const float* __restrict__ bias, unsigned short* __restrict__ out,
            signed char* __restrict__ hQ, float* __restrict__ hscale, int n) {
    gemm_body<RELU, AT>(blockIdx.x, in, Wt, bias, out, hQ, hscale, n);
}

// ---------------- FUSED: wfill blocks + layer-1 GEMM blocks -------------------
__global__ __launch_bounds__(256)
void k_wfgemm1(const int* __restrict__ csr_s, const float* __restrict__ dinv,
               float* __restrict__ csr_w, int nE, int n, int wfB,
               const float* __restrict__ x, const unsigned short* __restrict__ Wt,
               unsigned short* __restrict__ hW,
               signed char* __restrict__ hQ, float* __restrict__ hscale) {
    if (blockIdx.x < wfB) {
        int e = blockIdx.x * 256 + threadIdx.x;
        if (e < nE) {
            int s = csr_s[e];
            s = max(0, min(s, n - 1));
            csr_w[e] = dinv[s];
        }
        return;
    }
    gemm_body<false, float>(blockIdx.x - wfB, x, Wt, nullptr, hW, hQ, hscale, n);
}

// ---------------- aggregation: R15 readlane 2-node form, int8 gathers ---------
// Row = 64B int8 (1 cache line, was 2). Row scale folded into per-edge w
// during the metadata phase (hscale is 400KB -> L2-resident, no HBM cost).
// Self term stays bf16 (coalesced streaming read, full precision).
template<int LAYER>
__global__ __launch_bounds__(256)
void k_agg(const signed char* __restrict__ hQ, const float* __restrict__ hscale,
           const unsigned short* __restrict__ hW,
           const int* __restrict__ rowptr, const int* __restrict__ rowend,
           const int* __restrict__ csr_s, const float* __restrict__ csr_w,
           const float* __restrict__ dinv,
           unsigned short* __restrict__ aggb, int n, int nE) {
    const int lane = threadIdx.x & 63;
    const int wid  = threadIdx.x >> 6;
    const int nA = blockIdx.x * 8 + wid * 2;
    const int nB = nA + 1;
    if (nA >= n) return;
    const bool vB = (nB < n);

    int rowA = rowptr[nA], endA = rowend[nA];
    rowA = max(0, min(rowA, nE)); endA = max(rowA, min(endA, nE));
    endA = min(endA, rowA + MAXDEG);
    int rowB = 0, endB = 0;
    if (vB) {
        rowB = rowptr[nB]; endB = rowend[nB];
        rowB = max(0, min(rowB, nE)); endB = max(rowB, min(endB, nE));
        endB = min(endB, rowB + MAXDEG);
    }
    const float diA = dinv[nA];
    const float diB = vB ? dinv[nB] : 0.f;

    float a0 = diA * diA * bf2f(hW[(size_t)nA * 64 + lane]);
    float a1 = 0.f, a2 = 0.f, a3 = 0.f;
    float b0 = vB ? diB * diB * bf2f(hW[(size_t)nB * 64 + lane]) : 0.f;
    float b1 = 0.f, b2 = 0.f, b3 = 0.f;

    const int nm1 = n - 1;
    int baseA = rowA, baseB = rowB;
    while (baseA < endA || baseB < endB) {
        int mA = max(0, min(32, endA - baseA));
        int mB = max(0, min(32, endB - baseB));
        int   s_l = 0;
        float w_l = 0.f;
        if (lane < 32) {
            if (lane < mA) {
                int e = baseA + lane;
                int sl = csr_s[e];
                sl = max(0, min(sl, nm1));
                s_l = sl;
                w_l = csr_w[e] * diA * hscale[sl];   // scale folded into w
            }
        } else {
            int l2 = lane - 32;
            if (l2 < mB) {
                int e = baseB + l2;
                int sl = csr_s[e];
                sl = max(0, min(sl, nm1));
                s_l = sl;
                w_l = csr_w[e] * diB * hscale[sl];
            }
        }
        const unsigned w_u = __float_as_uint(w_l);
        const int m = max(mA, mB);
        int j = 0;
        for (; j + 4 <= m; j += 4) {
            int sA0 = __builtin_amdgcn_readlane(s_l, j    );
            int sA1 = __builtin_amdgcn_readlane(s_l, j + 1);
            int sA2 = __builtin_amdgcn_readlane(s_l, j + 2);
            int sA3 = __builtin_amdgcn_readlane(s_l, j + 3);
            int sB0 = __builtin_amdgcn_readlane(s_l, j + 32);
            int sB1 = __builtin_amdgcn_readlane(s_l, j + 33);
            int sB2 = __builtin_amdgcn_readlane(s_l, j + 34);
            int sB3 = __builtin_amdgcn_readlane(s_l, j + 35);
            float wA0 = __uint_as_float(__builtin_amdgcn_readlane(w_u, j));
            float wA1 = __uint_as_float(__builtin_amdgcn_readlane(w_u, j + 1));
            float wA2 = __uint_as_float(__builtin_amdgcn_readlane(w_u, j + 2));
            float wA3 = __uint_as_float(__builtin_amdgcn_readlane(w_u, j + 3));
            float wB0 = __uint_as_float(__builtin_amdgcn_readlane(w_u, j + 32));
            float wB1 = __uint_as_float(__builtin_amdgcn_readlane(w_u, j + 33));
            float wB2 = __uint_as_float(__builtin_amdgcn_readlane(w_u, j + 34));
            float wB3 = __uint_as_float(__builtin_amdgcn_readlane(w_u, j + 35));
            float hA0 = (float)hQ[(size_t)sA0 * 64 + lane];
            float hA1 = (float)hQ[(size_t)sA1 * 64 + lane];
            float hA2 = (float)hQ[(size_t)sA2 * 64 + lane];
            float hA3 = (float)hQ[(size_t)sA3 * 64 + lane];
            float hB0 = (float)hQ[(size_t)sB0 * 64 + lane];
            float hB1 = (float)hQ[(size_t)sB1 * 64 + lane];
            float hB2 = (float)hQ[(size_t)sB2 * 64 + lane];
            float hB3 = (float)hQ[(size_t)sB3 * 64 + lane];
            a0 += wA0 * hA0; a1 += wA1 * hA1;
            a2 += wA2 * hA2; a3 += wA3 * hA3;
            b0 += wB0 * hB0; b1 += wB1 * hB1;
            b2 += wB2 * hB2; b3 += wB3 * hB3;
        }
        for (; j < m; j++) {
            int   sA = __builtin_amdgcn_readlane(s_l, j);
            int   sB = __builtin_amdgcn_readlane(s_l, j + 32);
            float wA = __uint_as_float(__builtin_amdgcn_readlane(w_u, j));
            float wB = __uint_as_float(__builtin_amdgcn_readlane(w_u, j + 32));
            a0 += wA * (float)hQ[(size_t)sA * 64 + lane];
            b0 += wB * (float)hQ[(size_t)sB * 64 + lane];
        }
        baseA += mA;
        baseB += mB;
    }
    aggb[(size_t)nA * 64 + lane] = f2bf((a0 + a1) + (a2 + a3));
    if (vB) aggb[(size_t)nB * 64 + lane] = f2bf((b0 + b1) + (b2 + b3));
}

// ---------------- pooling (run-length pre-reduce; few atomics) ----------------
__global__ void k_pool(const unsigned short* __restrict__ aggb,
                       const int* __restrict__ batch,
                       float* __restrict__ pool, float* __restrict__ cnt, int n) {
    const int lane = threadIdx.x;       // 64 threads
    const int base = blockIdx.x * 64;
    int g_cur = -1, run = 0;
    float acc = 0.f;
    for (int j = 0; j < 64; j++) {
        int node = base + j;
        if (node >= n) break;
        int g = batch[node];
        if (g != g_cur) {
            if (g_cur >= 0) {
                atomAddF(&pool[g_cur * 64 + lane], acc);
                if (lane == 0) atomAddF(&cnt[g_cur], (float)run);
            }
            g_cur = g; acc = 0.f; run = 0;
        }
        acc += bf2f(aggb[(size_t)node * 64 + lane]);
        run++;
    }
    if (g_cur >= 0) {
        atomAddF(&pool[g_cur * 64 + lane], acc);
        if (lane == 0) atomAddF(&cnt[g_cur], (float)run);
    }
}

// ---------------- classifier ----------------
__global__ void k_final(const float* __restrict__ pool, const float* __restrict__ cnt,
                        const float* __restrict__ b3, const float* __restrict__ Wl,
                        const float* __restrict__ bl, float* __restrict__ out) {
    __shared__ float s[64];
    const int g = blockIdx.x, t = threadIdx.x;
    float c = fmaxf(cnt[g], 1.0f);
    s[t] = pool[g * 64 + t] / c + b3[t];
    __syncthreads();
    if (t < 10) {
        float acc = bl[t];
#pragma unroll
        for (int k = 0; k < 64; k++) acc += s[k] * Wl[k * 10 + t];
        out[g * 10 + t] = acc;
    }
}

extern "C" void kernel_launch(void* const* d_in, const int* in_sizes, int n_in,
                              void* d_out, int out_size, void* d_ws, size_t ws_size,
                              hipStream_t stream) {
    const float* x   = (const float*)d_in[0];
    const int*   ei  = (const int*)d_in[1];
    const int*   bat = (const int*)d_in[2];
    const float* W1  = (const float*)d_in[3];
    const float* b1  = (const float*)d_in[4];
    const float* W2  = (const float*)d_in[5];
    const float* b2  = (const float*)d_in[6];
    const float* W3  = (const float*)d_in[7];
    const float* b3  = (const float*)d_in[8];
    const float* Wl  = (const float*)d_in[9];
    const float* bl  = (const float*)d_in[10];
    float* out = (float*)d_out;

    const int N_ = in_sizes[0] / 64;
    const int E_ = in_sizes[1] / 2;
    const int G_ = out_size / 10;
    const int NB_ = (N_ + BNODES - 1) >> BSHIFT;
    const int bin_blocks = (E_ + EPB - 1) / EPB;

    // workspace layout
    char* p = (char*)d_ws;
    int*   staging = (int*)p;   p += (size_t)E_ * 4;
    int*   csr_s  = (int*)p;    p += (size_t)E_ * 4;
    float* csr_w  = (float*)p;  p += (size_t)E_ * 4;
    unsigned short* aggb = (unsigned short*)p; p += (size_t)N_ * 64 * 2;
    unsigned short* hW   = (unsigned short*)p; p += (size_t)N_ * 64 * 2;
    float* dinv   = (float*)p;  p += (size_t)N_ * 4;
    int*   rowptr = (int*)p;    p += (size_t)N_ * 4;
    int*   rowend = (int*)p;    p += (size_t)N_ * 4;
    float* pool   = (float*)p;  p += (size_t)G_ * 64 * 4;
    float* cnt    = (float*)p;  p += (size_t)G_ * 4;
    unsigned short* Wt = (unsigned short*)p; p += 3 * 4096 * 2;
    int*   bcnt   = (int*)p;    p += (size_t)(NB_ + 1) * 4;
    int*   bbase  = (int*)p;    p += (size_t)(NB_ + 1) * 4;
    int*   cnt_all = (int*)p;   p += (size_t)bin_blocks * NB_ * 4;
    signed char* hQ = (signed char*)p; p += (size_t)N_ * 64;
    float* hscale  = (float*)p; p += (size_t)N_ * 4;

    const int* srcp = ei;
    const int* dstp = ei + E_;

    // pool + cnt zeroed by k_bhist's extra block (they are contiguous)
    k_bhist<<<bin_blocks + 4, 256, 0, stream>>>(dstp, cnt_all, E_, NB_,
                                                bin_blocks, W1, W2, W3, Wt,
                                                pool, G_ * 64 + G_);
    k_colscan<<<(NB_ + 3) / 4, 256, 0, stream>>>(cnt_all, bcnt, bin_blocks, NB_);
    k_bscan<<<1, 256, 0, stream>>>(bcnt, bbase, NB_, E_);
    k_bucket<<<bin_blocks, 256, 0, stream>>>(srcp, dstp, bbase, cnt_all,
                                             staging, E_, NB_);
    k_sort<<<NB_, 256, 0, stream>>>(staging, bbase, csr_s, rowptr, rowend,
                                    dinv, N_, E_);

    const int gemm_blocks = (N_ + 63) / 64;
    const int agg_blocks  = (N_ + 7) / 8;
    const int wf_blocks   = (E_ + 255) / 256;

    // Fused wfill + Layer-1 GEMM (+ int8 quant)
    k_wfgemm1<<<wf_blocks + gemm_blocks, 256, 0, stream>>>(
        csr_s, dinv, csr_w, E_, N_, wf_blocks, x, Wt, hW, hQ, hscale);
    k_agg<1><<<agg_blocks, 256, 0, stream>>>(hQ, hscale, hW, rowptr, rowend,
                                             csr_s, csr_w, dinv, aggb, N_, E_);
    // Layer 2
    k_gemm<true, unsigned short><<<gemm_blocks, 256, 0, stream>>>(
        aggb, Wt + 4096, b1, hW, hQ, hscale, N_);
    k_agg<2><<<agg_blocks, 256, 0, stream>>>(hQ, hscale, hW, rowptr, rowend,
                                             csr_s, csr_w, dinv, aggb, N_, E_);
    // Layer 3
    k_gemm<true, unsigned short><<<gemm_blocks, 256, 0, stream>>>(
        aggb, Wt + 8192, b2, hW, hQ, hscale, N_);
    k_agg<3><<<agg_blocks, 256, 0, stream>>>(hQ, hscale, hW, rowptr, rowend,
                                             csr_s, csr_w, dinv, aggb, N_, E_);

    // Pool (b3 folded into final) + classifier
    k_pool<<<(N_ + 63) / 64, 64, 0, stream>>>(aggb, bat, pool, cnt, N_);
    k_final<<<G_, 64, 0, stream>>>(pool, cnt, b3, Wl, bl, out);
}